// Round 1
// 7879.308 us; speedup vs baseline: 1.0072x; 1.0072x over previous
//
#include <hip/hip_runtime.h>

#define NT 256          // threads per block
#define RT 16           // rows per block
#define AP 16           // activation LDS pitch (floats): act[col][AP], 16B-aligned rows of 4
#define WP 516          // weight-tile LDS pitch (floats): 512 + 4, float4-aligned
#define INN 256
#define HIDN 512
#define LATN 256
#define KCB 1024
#define BROWS 131072

// d_out element offsets (fp32 elements)
#define SC_OFF   33554432ull            // B*LAT
#define RS_OFF   33685504ull
#define LOSS_OFF 33816576ull
#define IDS_OFF  33816577ull

// ---------------------------------------------------------------------------
// Tiled fp32 GEMM layer, act (transposed [col][row], pitch AP) -> act in-place.
// Numerics bit-identical to the verified kernel: single accumulator per output,
// ascending-k fmaf chain, bias added with one __fadd_rn.
// Thread tile: 8 rows x COLS cols (wave-uniform row half -> act reads are
// full-wave LDS broadcasts). Weight staging: coalesced float4 global loads,
// transposed b64/b32 LDS writes. Explicit one-ahead register pipelining of
// both act (across tiles; act is layer-constant) and weight fragments.
// ---------------------------------------------------------------------------
template<int NCOLS>
__device__ __forceinline__ void gemm_layer(float* act, float* wbuf,
    const float* __restrict__ W, const float* __restrict__ bias,
    const int K, const bool do_relu, const int tid)
{
    constexpr int COLS = NCOLS / 128;    // 4 (512 cols) or 2 (256 cols)
    constexpr int CPT  = NCOLS / 256;    // staged cols per thread: 2 or 1
    const int rh = tid >> 7;             // 0/1 -> rows 8rh..8rh+7 (wave-uniform)
    const int r0 = rh << 3;
    const int c0 = (tid & 127) * COLS;
    const int sc = (CPT == 2) ? (((tid & 127) << 1) + (rh << 8)) : tid;
    const float* wp = W + (size_t)sc * K;
    const int kmask = K - 1;             // K is 256 or 512

    float acc[8][COLS];
#pragma unroll
    for (int i = 0; i < 8; ++i)
#pragma unroll
        for (int j = 0; j < COLS; ++j) acc[i][j] = 0.f;

    // prefetch weight tile 0 (coalesced along k)
    float4 pa0 = *(const float4*)(wp);
    float4 pa1 = *(const float4*)(wp + 4);
    float4 pb0, pb1;
    if (CPT == 2) {
        pb0 = *(const float4*)(wp + K);
        pb1 = *(const float4*)(wp + K + 4);
    }

    // act row pipeline: k=0 rows loaded up front (act constant across layer)
    float4 aL = *(const float4*)&act[r0];
    float4 aH = *(const float4*)&act[r0 + 4];

    const int ntiles = K >> 3;
    for (int kt = 0; kt < ntiles; ++kt) {
        __syncthreads();                 // everyone done reading wbuf
        {
            const float ua[8] = {pa0.x, pa0.y, pa0.z, pa0.w,
                                 pa1.x, pa1.y, pa1.z, pa1.w};
            if (CPT == 2) {
                const float ub[8] = {pb0.x, pb0.y, pb0.z, pb0.w,
                                     pb1.x, pb1.y, pb1.z, pb1.w};
#pragma unroll
                for (int kk = 0; kk < 8; ++kk) {
                    float2 t; t.x = ua[kk]; t.y = ub[kk];
                    *(float2*)&wbuf[kk * WP + sc] = t;
                }
            } else {
#pragma unroll
                for (int kk = 0; kk < 8; ++kk)
                    wbuf[kk * WP + sc] = ua[kk];
            }
        }
        __syncthreads();                 // tile visible
        // prefetch next tile; latency hidden under the compute below
        if (kt + 1 < ntiles) {
            const float* wn = wp + ((kt + 1) << 3);
            pa0 = *(const float4*)(wn);
            pa1 = *(const float4*)(wn + 4);
            if (CPT == 2) {
                pb0 = *(const float4*)(wn + K);
                pb1 = *(const float4*)(wn + K + 4);
            }
        }

        float wv0 = 0.f, wv1 = 0.f, wv2 = 0.f, wv3 = 0.f;
        if constexpr (COLS == 4) {
            const float4 t = *(const float4*)&wbuf[c0];
            wv0 = t.x; wv1 = t.y; wv2 = t.z; wv3 = t.w;
        } else {
            const float2 t = *(const float2*)&wbuf[c0];
            wv0 = t.x; wv1 = t.y;
        }
#pragma unroll
        for (int kk = 0; kk < 8; ++kk) {
            // one-ahead loads (act wraps to 0 at layer end: harmless, unused)
            const int kn = (((kt << 3) + kk + 1) & kmask) * AP + r0;
            const float4 aLn = *(const float4*)&act[kn];
            const float4 aHn = *(const float4*)&act[kn + 4];
            float wn0 = 0.f, wn1 = 0.f, wn2 = 0.f, wn3 = 0.f;
            if (kk < 7) {
                if constexpr (COLS == 4) {
                    const float4 t = *(const float4*)&wbuf[(kk + 1) * WP + c0];
                    wn0 = t.x; wn1 = t.y; wn2 = t.z; wn3 = t.w;
                } else {
                    const float2 t = *(const float2*)&wbuf[(kk + 1) * WP + c0];
                    wn0 = t.x; wn1 = t.y;
                }
            }
            const float ar[8] = {aL.x, aL.y, aL.z, aL.w,
                                 aH.x, aH.y, aH.z, aH.w};
#pragma unroll
            for (int i = 0; i < 8; ++i) acc[i][0] = fmaf(ar[i], wv0, acc[i][0]);
#pragma unroll
            for (int i = 0; i < 8; ++i) acc[i][1] = fmaf(ar[i], wv1, acc[i][1]);
            if constexpr (COLS == 4) {
#pragma unroll
                for (int i = 0; i < 8; ++i) acc[i][2] = fmaf(ar[i], wv2, acc[i][2]);
#pragma unroll
                for (int i = 0; i < 8; ++i) acc[i][3] = fmaf(ar[i], wv3, acc[i][3]);
            }
            aL = aLn; aH = aHn;
            if (kk < 7) { wv0 = wn0; wv1 = wn1; wv2 = wn2; wv3 = wn3; }
        }
    }
    __syncthreads();   // all reads of act done before overwriting
#pragma unroll
    for (int j = 0; j < COLS; ++j) {
        const float bv = bias[c0 + j];
#pragma unroll
        for (int i = 0; i < 8; ++i) {
            float v = __fadd_rn(acc[i][j], bv);   // single rounded add, like np
            if (do_relu) v = fmaxf(v, 0.f);
            act[(c0 + j) * AP + r0 + i] = v;
        }
    }
    __syncthreads();
}

// numpy pairwise sum of squares over 256 contiguous elements (replicates
// np.sum(z*z, axis=1) rounding exactly): 2x128 blocks, 8 accumulators each.
__device__ __forceinline__ float np_sumsq_row(const float* act, const int r)
{
    float half[2];
#pragma unroll
    for (int h = 0; h < 2; ++h) {
        const int base = h * 128;
        float rr[8];
#pragma unroll
        for (int j = 0; j < 8; ++j) {
            const float v = act[(base + j) * AP + r];
            rr[j] = __fmul_rn(v, v);
        }
        for (int i = 8; i < 128; i += 8) {
#pragma unroll
            for (int j = 0; j < 8; ++j) {
                const float v = act[(base + i + j) * AP + r];
                rr[j] = __fadd_rn(rr[j], __fmul_rn(v, v));
            }
        }
        half[h] = __fadd_rn(
            __fadd_rn(__fadd_rn(rr[0], rr[1]), __fadd_rn(rr[2], rr[3])),
            __fadd_rn(__fadd_rn(rr[4], rr[5]), __fadd_rn(rr[6], rr[7])));
    }
    return __fadd_rn(half[0], half[1]);
}

// ---------------------------------------------------------------------------
// NET: 0 = decoder (+VQ distance/argmin/outputs/loss), 1 = scaler, 2 = redshift
// ---------------------------------------------------------------------------
template<int NET>
__global__ __launch_bounds__(NT, 3)
void net_kernel(const float* __restrict__ z,
                const float* __restrict__ W0, const float* __restrict__ b0,
                const float* __restrict__ W1, const float* __restrict__ b1,
                const float* __restrict__ Wo, const float* __restrict__ bo,
                const float* __restrict__ cb, const float* __restrict__ cbn,
                float* __restrict__ loss_ws,
                float* __restrict__ out)
{
    __shared__ __align__(16) float act[HIDN * AP];   // 32768 B
    __shared__ __align__(16) float wbuf[8 * WP];     // 16512 B
    __shared__ float redv[32];
    __shared__ int   redk[32];
    __shared__ int   idT[RT];
    __shared__ float sz2[RT];

    const int tid  = threadIdx.x;
    const int row0 = blockIdx.x * RT;

    // stage z tile transposed: act[c][r]
#pragma unroll
    for (int it = 0; it < RT; ++it)
        act[tid * AP + it] = z[(size_t)(row0 + it) * INN + tid];
    __syncthreads();

    gemm_layer<512>(act, wbuf, W0, b0, INN,  true, tid);
    gemm_layer<512>(act, wbuf, W1, b1, HIDN, true, tid);

    if (NET == 0) {
        gemm_layer<256>(act, wbuf, Wo, bo, HIDN, false, tid);   // zl -> act[c][r]

        // per-row sum(zl^2) with numpy-pairwise rounding
        if (tid < RT) sz2[tid] = np_sumsq_row(act, tid);
        __syncthreads();

        // ---- VQ distance, replicating np fp32 rounding:
        //      d2 = fl( fl(sumz2 - fl(2*dot)) + cn )
        // thread tile: 8 rows (wave-uniform half) x 4 codebook entries
        const int rh  = tid >> 7;
        const int r0  = rh << 3;
        const int kq4 = (tid & 127) << 2;
        const int cc0 = tid >> 7;           // cb staging: row base
        const int k40 = (tid & 127) << 2;   // cb staging: col base
        float bestv[8]; int bestk[8];
#pragma unroll
        for (int i = 0; i < 8; ++i) { bestv[i] = 1e30f; bestk[i] = 0; }

        // prefetch cb tile (kh=0, ct=0) - coalesced b128
        float4 cpf[4];
#pragma unroll
        for (int e = 0; e < 4; ++e)
            cpf[e] = *(const float4*)&cb[(size_t)(cc0 + 2 * e) * KCB + k40];

        // act row pipeline (ca=0 up front)
        float4 aL = *(const float4*)&act[r0];
        float4 aH = *(const float4*)&act[r0 + 4];

        for (int kh = 0; kh < 2; ++kh) {
            float s[8][4];
#pragma unroll
            for (int i = 0; i < 8; ++i)
#pragma unroll
                for (int m = 0; m < 4; ++m) s[i][m] = 0.f;

            for (int ct = 0; ct < 32; ++ct) {
                __syncthreads();
#pragma unroll
                for (int e = 0; e < 4; ++e)
                    *(float4*)&wbuf[(cc0 + 2 * e) * WP + k40] = cpf[e];
                __syncthreads();
                // prefetch next cb tile (linear over kh,ct)
                const int nlin = (kh << 5) + ct + 1;
                if (nlin < 64) {
                    const int nct = nlin & 31, nkh = nlin >> 5;
#pragma unroll
                    for (int e = 0; e < 4; ++e)
                        cpf[e] = *(const float4*)&cb[
                            (size_t)(nct * 8 + cc0 + 2 * e) * KCB + (nkh << 9) + k40];
                }

                float4 cw = *(const float4*)&wbuf[kq4];
#pragma unroll
                for (int cc = 0; cc < 8; ++cc) {
                    // one-ahead act rows (wraps to ca=0 at half boundary:
                    // exactly what kh=1 restart needs)
                    const int can = (((ct << 3) + cc + 1) & 255) * AP + r0;
                    const float4 aLn = *(const float4*)&act[can];
                    const float4 aHn = *(const float4*)&act[can + 4];
                    float4 cwn;
                    if (cc < 7) cwn = *(const float4*)&wbuf[(cc + 1) * WP + kq4];
                    const float ar[8] = {aL.x, aL.y, aL.z, aL.w,
                                         aH.x, aH.y, aH.z, aH.w};
#pragma unroll
                    for (int i = 0; i < 8; ++i) s[i][0] = fmaf(ar[i], cw.x, s[i][0]);
#pragma unroll
                    for (int i = 0; i < 8; ++i) s[i][1] = fmaf(ar[i], cw.y, s[i][1]);
#pragma unroll
                    for (int i = 0; i < 8; ++i) s[i][2] = fmaf(ar[i], cw.z, s[i][2]);
#pragma unroll
                    for (int i = 0; i < 8; ++i) s[i][3] = fmaf(ar[i], cw.w, s[i][3]);
                    aL = aLn; aH = aHn;
                    if (cc < 7) cw = cwn;
                }
            }
            // fold into running argmin with np's exact rounding sequence
#pragma unroll
            for (int m = 0; m < 4; ++m) {
                const int kab = (kh << 9) + kq4 + m;
                const float cn = cbn[kab];
#pragma unroll
                for (int i = 0; i < 8; ++i) {
                    const float t = __fsub_rn(sz2[r0 + i],
                                              __fmul_rn(2.f, s[i][m]));
                    const float d = __fadd_rn(t, cn);
                    if (d < bestv[i]) { bestv[i] = d; bestk[i] = kab; }
                }
            }
        }

        // ---- cross-thread argmin reduce: wave shuffle tree, then 2 waves/row
        const int wid  = tid >> 6;
        const int lane = tid & 63;
#pragma unroll
        for (int i = 0; i < 8; ++i) {
            float v = bestv[i]; int k = bestk[i];
#pragma unroll
            for (int off = 1; off < 64; off <<= 1) {
                const float v2 = __shfl_xor(v, off);
                const int   k2 = __shfl_xor(k, off);
                if (v2 < v || (v2 == v && k2 < k)) { v = v2; k = k2; }
            }
            if (lane == 0) { redv[wid * 8 + i] = v; redk[wid * 8 + i] = k; }
        }
        __syncthreads();
        if (tid < RT) {
            const int w0 = (tid >> 3) << 1;   // rows 0-7: waves 0,1; 8-15: waves 2,3
            const int ii = tid & 7;
            float v = redv[w0 * 8 + ii]; int k = redk[w0 * 8 + ii];
            const float v2 = redv[(w0 + 1) * 8 + ii];
            const int   k2 = redk[(w0 + 1) * 8 + ii];
            if (v2 < v || (v2 == v && k2 < k)) { v = v2; k = k2; }
            idT[tid] = k;
            out[IDS_OFF + row0 + tid] = (float)k;
        }
        __syncthreads();

        // ---- epilogue: z_q_st = z_q (forward), loss partial
        float lsum = 0.f;
#pragma unroll
        for (int r = 0; r < RT; ++r) {
            const int id = idT[r];
            const float zv = act[tid * AP + r];
            const float q  = cb[(size_t)tid * KCB + id] - zv;
            out[(size_t)(row0 + r) * LATN + tid] = zv + q;
            lsum += q * q;
        }
        lsum += __shfl_down(lsum, 32);
        lsum += __shfl_down(lsum, 16);
        lsum += __shfl_down(lsum, 8);
        lsum += __shfl_down(lsum, 4);
        lsum += __shfl_down(lsum, 2);
        lsum += __shfl_down(lsum, 1);
        if ((tid & 63) == 0)
            atomicAdd(loss_ws, lsum * (1.0f / 33554432.0f));   // 1/(B*LAT)
    } else {
        // ---- out_dim == 1: out[r] = h2[r] . Wo + bo
        const int r  = tid & 15;
        const int kg = tid >> 4;
        float p = 0.f;
#pragma unroll
        for (int kk = 0; kk < 32; ++kk) {
            const int k = (kg << 5) + kk;
            p = fmaf(act[k * AP + r], Wo[k], p);
        }
        wbuf[kg * 16 + r] = p;
        __syncthreads();
        if (tid < RT) {
            float s2 = bo[0];
            for (int kg2 = 0; kg2 < 16; ++kg2) s2 += wbuf[kg2 * 16 + tid];
            if (NET == 2) s2 = fmaxf(s2, 0.f);
            const size_t off = (NET == 1) ? SC_OFF : RS_OFF;
            out[off + row0 + tid] = s2;
        }
    }
}

// cbnorm[k]: replicate np.sum(cb*cb, axis=0) - strided axis-0 reduction is
// SEQUENTIAL (no pairwise) over c ascending, squares rounded separately.
__global__ void prep_kernel(const float* __restrict__ cb, float* __restrict__ ws)
{
    const int k = blockIdx.x * NT + threadIdx.x;
    float a = 0.f;
    for (int c = 0; c < LATN; ++c) {
        const float v = cb[(size_t)c * KCB + k];
        a = __fadd_rn(a, __fmul_rn(v, v));
    }
    ws[k] = a;
    if (k == 0) ws[KCB] = 0.f;
}

__global__ void fin_kernel(const float* __restrict__ ws, float* __restrict__ out)
{
    if (threadIdx.x == 0) out[LOSS_OFF] = ws[KCB];
}

extern "C" void kernel_launch(void* const* d_in, const int* in_sizes, int n_in,
                              void* d_out, int out_size, void* d_ws, size_t ws_size,
                              hipStream_t stream)
{
    const float* z    = (const float*)d_in[0];
    const float* dW0  = (const float*)d_in[1];
    const float* db0  = (const float*)d_in[2];
    const float* dW1  = (const float*)d_in[3];
    const float* db1  = (const float*)d_in[4];
    const float* dWo  = (const float*)d_in[5];
    const float* dbo  = (const float*)d_in[6];
    const float* sW0  = (const float*)d_in[7];
    const float* sb0  = (const float*)d_in[8];
    const float* sW1  = (const float*)d_in[9];
    const float* sb1  = (const float*)d_in[10];
    const float* sWo  = (const float*)d_in[11];
    const float* sbo  = (const float*)d_in[12];
    const float* rW0  = (const float*)d_in[13];
    const float* rb0  = (const float*)d_in[14];
    const float* rW1  = (const float*)d_in[15];
    const float* rb1  = (const float*)d_in[16];
    const float* rWo  = (const float*)d_in[17];
    const float* rbo  = (const float*)d_in[18];
    const float* cb   = (const float*)d_in[19];

    float* out = (float*)d_out;
    float* ws = (float*)d_ws;           // [0..1024) cbnorm, [1024] loss accum

    prep_kernel<<<KCB / NT, NT, 0, stream>>>(cb, ws);

    const int grid = BROWS / RT;        // 8192 blocks
    net_kernel<0><<<grid, NT, 0, stream>>>(z, dW0, db0, dW1, db1, dWo, dbo,
                                           cb, ws, ws + KCB, out);
    net_kernel<1><<<grid, NT, 0, stream>>>(z, sW0, sb0, sW1, sb1, sWo, sbo,
                                           cb, ws, ws + KCB, out);
    net_kernel<2><<<grid, NT, 0, stream>>>(z, rW0, rb0, rW1, rb1, rWo, rbo,
                                           cb, ws, ws + KCB, out);

    fin_kernel<<<1, 64, 0, stream>>>(ws, out);
}